// Round 1
// baseline (194.806 us; speedup 1.0000x reference)
//
#include <hip/hip_runtime.h>
#include <hip/hip_bf16.h>
#include <stdint.h>

typedef __bf16 bf16x8 __attribute__((ext_vector_type(8)));
typedef float  f32x16 __attribute__((ext_vector_type(16)));

#define NROWS   131072
#define CDIM    256
#define T_INV   5.0f
#define K2EXP   7.2134752044448170f   /* 1/(T*ln2) = log2(e)/T */
#define LN2F    0.6931471805599453f

__device__ __forceinline__ float wave_red_sum64(float s) {
  #pragma unroll
  for (int m = 1; m <= 32; m <<= 1) s += __shfl_xor(s, m, 64);
  return s;
}

__device__ __forceinline__ unsigned short f2bf(float f) {
  __bf16 h = (__bf16)f;
  return __builtin_bit_cast(unsigned short, h);
}

// rnorm[row] = 1/||l2[row]||  (4 rows per 256-thread block, one wave per row)
__global__ __launch_bounds__(256) void k_rnorm(const float* __restrict__ l2,
                                               float* __restrict__ rnorm) {
  const int w = threadIdx.x >> 6, l = threadIdx.x & 63;
  const int row = blockIdx.x * 4 + w;
  const float4 v = *(const float4*)(l2 + (size_t)row * CDIM + l * 4);
  float s = v.x * v.x + v.y * v.y + v.z * v.z + v.w * v.w;
  s = wave_red_sum64(s);
  if (l == 0) rnorm[row] = rsqrtf(s);
}

// ghat: row-normalized g_enc as bf16, stored pre-swizzled:
// byte kb of row r lands at r*512 + (kb ^ ((r&7)<<4))
__global__ __launch_bounds__(256) void k_ghat(const float* __restrict__ g,
                                              char* __restrict__ ghat) {
  const int w = threadIdx.x >> 6, l = threadIdx.x & 63;
  const int row = blockIdx.x * 4 + w;
  const float4 v = *(const float4*)(g + (size_t)row * CDIM + l * 4);
  float s = v.x * v.x + v.y * v.y + v.z * v.z + v.w * v.w;
  s = wave_red_sum64(s);
  const float rn = rsqrtf(s);
  ushort4 o;
  o.x = f2bf(v.x * rn); o.y = f2bf(v.y * rn);
  o.z = f2bf(v.z * rn); o.w = f2bf(v.w * rn);
  const int off = row * 512 + ((l * 8) ^ ((row & 7) << 4));
  *(ushort4*)(ghat + off) = o;
}

// Main fused kernel: per-wave 64 rows (A in registers, k=256 resident),
// ghat streamed through LDS in 128-col chunks, exp/rowsum fused epilogue.
__global__ __launch_bounds__(256, 2) void k_main(
    const float* __restrict__ l2, const float* __restrict__ rnorm,
    const char* __restrict__ ghat, float* __restrict__ out) {
  __shared__ __align__(16) char smem[64 * 1024 + 1024];
  float* posl = (float*)(smem + 64 * 1024);

  const int tid = threadIdx.x;
  const int w   = tid >> 6;
  const int l   = tid & 63;
  const int lm  = l & 31;
  const int lh  = l >> 5;
  const int wrb = blockIdx.x * 256 + w * 64;  // wave's first row
  const int p   = wrb >> 7;                   // positive column (wave-uniform)
  const int pcf = p >> 5;                     // which 32-col fragment holds it

  auto stage = [&](int c) {
    const char* gsrc = ghat + c * 65536 + w * 16384 + l * 16;
    #pragma unroll
    for (int i = 0; i < 16; ++i) {
      __builtin_amdgcn_global_load_lds(
          (const __attribute__((address_space(1))) void*)(gsrc + i * 1024),
          (__attribute__((address_space(3))) void*)(smem + w * 16384 + i * 1024),
          16, 0, 0);
    }
  };

  stage(0);  // overlap first B-chunk staging with A load

  // Load + normalize A fragments: af[g][s] covers rows wrb+g*32+lm,
  // k = s*16 + lh*8 .. +8  (32x32x16 A operand, 8 contiguous bf16/lane)
  bf16x8 af[2][16];
  #pragma unroll
  for (int g2 = 0; g2 < 2; ++g2) {
    const int row = wrb + g2 * 32 + lm;
    const float rn = rnorm[row];
    const float* rp = l2 + (size_t)row * CDIM + lh * 8;
    #pragma unroll
    for (int s = 0; s < 16; ++s) {
      const float4 a = *(const float4*)(rp + s * 16);
      const float4 b = *(const float4*)(rp + s * 16 + 4);
      bf16x8 f;
      f[0] = (__bf16)(a.x * rn); f[1] = (__bf16)(a.y * rn);
      f[2] = (__bf16)(a.z * rn); f[3] = (__bf16)(a.w * rn);
      f[4] = (__bf16)(b.x * rn); f[5] = (__bf16)(b.y * rn);
      f[6] = (__bf16)(b.z * rn); f[7] = (__bf16)(b.w * rn);
      af[g2][s] = f;
    }
  }

  float rs[2][16];
  #pragma unroll
  for (int g2 = 0; g2 < 2; ++g2)
    #pragma unroll
    for (int j = 0; j < 16; ++j) rs[g2][j] = 0.f;

  for (int c = 0; c < 8; ++c) {
    __syncthreads();  // chunk c staged (and previous compute done)
    #pragma unroll
    for (int cf = 0; cf < 4; ++cf) {
      const int col_l = cf * 32 + lm;
      const int sw = (col_l & 7) << 4;
      f32x16 acc0 = {0.f};
      f32x16 acc1 = {0.f};
      #pragma unroll
      for (int s = 0; s < 16; ++s) {
        const int off = col_l * 512 + ((s * 32 + lh * 16) ^ sw);
        const uint4 raw = *(const uint4*)(smem + off);
        const bf16x8 bfr = __builtin_bit_cast(bf16x8, raw);
        acc0 = __builtin_amdgcn_mfma_f32_32x32x16_bf16(af[0][s], bfr, acc0, 0, 0, 0);
        acc1 = __builtin_amdgcn_mfma_f32_32x32x16_bf16(af[1][s], bfr, acc1, 0, 0, 0);
      }
      // fused epilogue: exp + rowsum accumulate
      #pragma unroll
      for (int j = 0; j < 16; ++j) {
        rs[0][j] += __builtin_amdgcn_exp2f(acc0[j] * K2EXP);
        rs[1][j] += __builtin_amdgcn_exp2f(acc1[j] * K2EXP);
      }
      // park positive-column logits (2 lanes of the wave) in LDS
      if (pcf == c * 4 + cf && lm == (p & 31)) {
        #pragma unroll
        for (int j = 0; j < 16; ++j) {
          const int r0 = (j & 3) + 8 * (j >> 2) + 4 * lh;
          posl[w * 64 + r0]      = acc0[j];
          posl[w * 64 + 32 + r0] = acc1[j];
        }
      }
    }
    __syncthreads();  // all waves done reading before restage
    if (c < 7) stage(c + 1);
  }

  // reduce row sums over the 32 column-lanes of each half
  #pragma unroll
  for (int g2 = 0; g2 < 2; ++g2)
    #pragma unroll
    for (int j = 0; j < 16; ++j) {
      float v = rs[g2][j];
      #pragma unroll
      for (int m = 1; m <= 16; m <<= 1) v += __shfl_xor(v, m, 64);
      rs[g2][j] = v;
    }

  if (lm == 0) {  // lanes 0 and 32: 32 rows each
    float local = 0.f;
    #pragma unroll
    for (int g2 = 0; g2 < 2; ++g2)
      #pragma unroll
      for (int j = 0; j < 16; ++j) {
        const int r0 = g2 * 32 + (j & 3) + 8 * (j >> 2) + 4 * lh;
        const float cpos = posl[w * 64 + r0];
        const float ep = __builtin_amdgcn_exp2f(cpos * K2EXP);
        const float S = rs[g2][j] - ep;           // sum excluding positive
        local += __builtin_amdgcn_logf(S) * LN2F - cpos * T_INV;
      }
    atomicAdd(out, local * (1.0f / (float)NROWS));
  }
}

extern "C" void kernel_launch(void* const* d_in, const int* in_sizes, int n_in,
                              void* d_out, int out_size, void* d_ws, size_t ws_size,
                              hipStream_t stream) {
  (void)in_sizes; (void)n_in; (void)out_size; (void)ws_size;
  const float* l2 = (const float*)d_in[0];   // [131072, 256] fp32
  const float* g  = (const float*)d_in[1];   // [1024, 256] fp32
  float* out = (float*)d_out;

  float* rnorm = (float*)d_ws;                          // 512 KB
  char*  ghat  = (char*)d_ws + (512 << 10);             // 512 KB (bf16, swizzled)

  hipMemsetAsync(d_out, 0, sizeof(float), stream);
  k_rnorm<<<NROWS / 4, 256, 0, stream>>>(l2, rnorm);
  k_ghat<<<1024 / 4, 256, 0, stream>>>(g, ghat);
  k_main<<<NROWS / 256, 256, 0, stream>>>(l2, rnorm, ghat, out);
}